// Round 2
// baseline (373.301 us; speedup 1.0000x reference)
//
#include <hip/hip_runtime.h>
#include <math.h>

#define NUM_BINS 15
#define CCLS 100
#define BLOCK 256
#define GRID 1024
#define WPB (BLOCK / 64)     // 4 waves per block -> 4096 waves
#define NXCD 8

// Row-per-lane streaming ECE. Each lane owns one full row of 100 logits:
//   25 aligned float4 loads -> registers; in-register max + exp-sum (4
//   parallel chains); target logit re-read (L1-hot); statically-indexed
//   per-lane bin accumulators. NO LDS staging, NO s_waitcnt choke points,
//   NO cross-lane ops in the hot loop -> per-wave MLP ~25.6 KB, compiler
//   free to pipeline loads across the whole sweep.
// __launch_bounds__(256,4): cap 128 VGPR -> 4 blocks/CU = 16 waves/CU, and
// GRID=1024 makes all blocks resident with exactly 2 row-iterations/wave.
__global__ __launch_bounds__(BLOCK, 4) void ece_rows(
    const float* __restrict__ logits,
    const int* __restrict__ labels,
    float* __restrict__ ws,   // [0..14]: sum(conf-pred); int ticket at ws[48]
    float* __restrict__ out,
    int n_rows)
{
    __shared__ float s_bin[NUM_BINS];
    __shared__ int s_last;

    const int tid  = threadIdx.x;
    const int lane = tid & 63;
    const int wave = tid >> 6;

    if (tid < NUM_BINS) s_bin[tid] = 0.f;
    __syncthreads();

    // bijective XCD swizzle (GRID%8==0): XCD x gets a contiguous 128-block
    // span -> each XCD streams a contiguous ~26 MB region of logits.
    const int b  = blockIdx.x;
    const int bp = (b & 7) * (GRID / NXCD) + (b >> 3);
    const int gw = bp * WPB + wave;                 // 0..4095
    const int n_waves = GRID * WPB;
    const int rpw = n_rows / n_waves;               // 128 rows per wave
    const int nit = rpw >> 6;                       // 2 iterations of 64 rows
    const int row_base = gw * rpw;

    float acc[NUM_BINS];
    #pragma unroll
    for (int k = 0; k < NUM_BINS; ++k) acc[k] = 0.f;

    for (int it = 0; it < nit; ++it) {
        const int row = row_base + it * 64 + lane;
        const float* rowp = logits + (size_t)row * CCLS;
        const float4* rp = (const float4*)rowp;     // 400 B rows: 16B-aligned
        const int lab = labels[row];                // coalesced across lanes

        float4 ma = make_float4(-1e30f, -1e30f, -1e30f, -1e30f);
        float4 ea = make_float4(0.f, 0.f, 0.f, 0.f);
        #pragma unroll
        for (int k = 0; k < 25; ++k) {
            const float4 v = rp[k];
            ma.x = fmaxf(ma.x, v.x);
            ma.y = fmaxf(ma.y, v.y);
            ma.z = fmaxf(ma.z, v.z);
            ma.w = fmaxf(ma.w, v.w);
            ea.x += __expf(v.x);
            ea.y += __expf(v.y);
            ea.z += __expf(v.z);
            ea.w += __expf(v.w);
        }
        const float m = fmaxf(fmaxf(ma.x, ma.y), fmaxf(ma.z, ma.w));
        const float e = (ea.x + ea.y) + (ea.z + ea.w);
        const float xt = rowp[lab];                 // L1-hot re-read

        const float inv  = 1.0f / e;
        const float conf = __expf(m) * inv;
        const float diff = conf - __expf(xt) * inv;
        int bin = (int)(conf * (float)NUM_BINS);
        bin = bin > NUM_BINS - 1 ? NUM_BINS - 1 : bin;

        // statically-indexed accumulate (runtime-indexed array would spill
        // to scratch); 30 VALU per 64 rows — VALU is idle anyway.
        #pragma unroll
        for (int q = 0; q < NUM_BINS; ++q)
            acc[q] += (bin == q) ? diff : 0.f;
    }

    // wave-level butterfly reduce each bin, then one LDS atomic per bin
    // (15 distinct addresses, conflict-free, single instruction).
    float mine = 0.f;
    #pragma unroll
    for (int q = 0; q < NUM_BINS; ++q) {
        float v = acc[q];
        #pragma unroll
        for (int off = 1; off < 64; off <<= 1) v += __shfl_xor(v, off);
        if (lane == q) mine = v;
    }
    __syncthreads();   // s_bin init visible (already, but cheap & safe)
    if (lane < NUM_BINS) atomicAdd(&s_bin[lane], mine);

    __syncthreads();
    if (tid < NUM_BINS) atomicAdd(&ws[tid], s_bin[tid]);
    __syncthreads();

    // ---- ticket: last block folds ECE = sum_b |ws[b]| / N ----
    if (tid == 0) {
        __threadfence();
        const int tkt = atomicAdd((int*)(ws + 48), 1);
        s_last = (tkt == GRID - 1) ? 1 : 0;
    }
    __syncthreads();
    if (s_last && tid < 64) {
        __threadfence();
        float contrib = 0.f;
        if (tid < NUM_BINS) {
            const float v = __hip_atomic_load(&ws[tid], __ATOMIC_RELAXED,
                                              __HIP_MEMORY_SCOPE_AGENT);
            contrib = fabsf(v);
        }
        #pragma unroll
        for (int off = 32; off >= 1; off >>= 1)
            contrib += __shfl_xor(contrib, off);
        if (tid == 0) out[0] = contrib / (float)n_rows;
    }
}

extern "C" void kernel_launch(void* const* d_in, const int* in_sizes, int n_in,
                              void* d_out, int out_size, void* d_ws, size_t ws_size,
                              hipStream_t stream)
{
    const float* logits = (const float*)d_in[0];
    const int*   labels = (const int*)d_in[1];
    float* out = (float*)d_out;
    float* ws  = (float*)d_ws;

    const int n_rows = in_sizes[1];   // 524288 = 4096 waves * 128 rows exactly

    // ws re-poisoned to 0xAA before every timed launch — zero accumulators+ticket.
    hipMemsetAsync(ws, 0, 64 * sizeof(float), stream);

    ece_rows<<<dim3(GRID), dim3(BLOCK), 0, stream>>>(logits, labels, ws, out, n_rows);
}

// Round 3
// 317.481 us; speedup vs baseline: 1.1758x; 1.1758x over previous
//
#include <hip/hip_runtime.h>
#include <math.h>

#define NUM_BINS 15
#define CCLS 100
#define BLOCK 256
#define GRID 768                 // 3 blocks/CU exactly (LDS-limited), 768%8==0
#define WPB (BLOCK / 64)         // 4 waves per block
#define TROWS 16                 // rows per tile
#define TFLOATS (TROWS * CCLS)   // 1600 floats = 6400 B per tile
#define NXCD 8
#define MAXT 11                  // max tiles per wave (tq+1)
#define LABW (MAXT * TROWS)      // labels per wave = 176

// --- global->LDS DMA helpers (size must be a literal constant) ---
__device__ __forceinline__ void dma16(const float* gp, float* lp) {
    __builtin_amdgcn_global_load_lds(
        (const __attribute__((address_space(1))) void*)gp,
        (__attribute__((address_space(3))) void*)lp, 16, 0, 0);
}
__device__ __forceinline__ void dma4(const float* gp, float* lp) {
    __builtin_amdgcn_global_load_lds(
        (const __attribute__((address_space(1))) void*)gp,
        (__attribute__((address_space(3))) void*)lp, 4, 0, 0);
}

// Round-3 fix: labels are preloaded to LDS ONCE per block, so the hot loop's
// only VMEM ops are the 7 tile DMAs. The counted s_waitcnt vmcnt(7) then
// truly overlaps tile i+1's loads with tile i's consume. (Rounds 0-2 all
// consumed a label from the same VMEM window, forcing a compiler-inserted
// vmcnt(0) full drain every iteration — the pipeline never existed.)
__global__ __launch_bounds__(BLOCK) void ece_stream(
    const float* __restrict__ logits,
    const int* __restrict__ labels,
    float* __restrict__ ws,   // [0..14]: sum(conf-pred); int ticket at ws[48]
    float* __restrict__ out,
    int n_rows)
{
    __shared__ float s_buf[WPB][2][TFLOATS];       // 51200 B
    __shared__ int   s_lab[WPB * LABW];            // 2816 B
    __shared__ float s_bin[NUM_BINS];
    __shared__ int s_last;

    const int tid  = threadIdx.x;
    const int lane = tid & 63;
    const int wave = tid >> 6;

    if (tid < NUM_BINS) s_bin[tid] = 0.f;

    // XCD swizzle: XCD x (= b%8) gets a contiguous span of 96 blocks.
    const int b  = blockIdx.x;
    const int bp = (b & 7) * (GRID / NXCD) + (b >> 3);
    const int gw = bp * WPB + wave;                 // 0..3071
    const int n_waves = GRID * WPB;

    // contiguous tile distribution: first `trem` waves get tq+1 tiles
    const int ntiles = n_rows / TROWS;              // 32768
    const int tq   = ntiles / n_waves;              // 10
    const int trem = ntiles - tq * n_waves;         // 2048
    const int nt = tq + (gw < trem ? 1 : 0);
    const int t0 = gw * tq + (gw < trem ? gw : trem);

    // ---- block-wide label preload: rows [T0*16, T0*16 + NT*16) ----
    {
        const int gw0 = bp * WPB;                   // block's first wave
        const int T0  = gw0 * tq + (gw0 < trem ? gw0 : trem);
        const int NTb = (t0 - T0) + nt + (wave < WPB - 1 ? 0 : 0);
        // block's total tiles = sum over its 4 waves; compute span end from
        // last wave directly:
        const int gwL = gw0 + WPB - 1;
        const int tL0 = gwL * tq + (gwL < trem ? gwL : trem);
        const int ntL = tq + (gwL < trem ? 1 : 0);
        const int NROW = (tL0 + ntL - T0) * TROWS;  // 640..704
        (void)NTb;
        for (int j = tid; j < NROW; j += BLOCK)
            s_lab[j] = labels[T0 * TROWS + j];
        // this wave's label base within s_lab:
    }
    __syncthreads();
    const int gw0 = bp * WPB;
    const int T0  = gw0 * tq + (gw0 < trem ? gw0 : trem);
    const int* my_lab = s_lab + (t0 - T0) * TROWS;  // wave's first label

    const int q = lane >> 4;          // quarter-row 0..3 (25 cols each)
    const int r = lane & 15;          // row within tile

    float* cur = s_buf[wave][0];
    float* nxt = s_buf[wave][1];

    // ---- prologue: stage tile t0 (7 VMEM in flight) ----
    {
        const float* g = logits + (size_t)t0 * TFLOATS;
        #pragma unroll
        for (int k = 0; k < 6; ++k)
            dma16(g + k * 256 + lane * 4, cur + k * 256);
        dma4(g + 1536 + lane, cur + 1536);
    }

    for (int i = 0; i < nt; ++i) {
        if (i + 1 < nt) {
            // prior iteration's ds_reads of `nxt` are retired before the DMA
            // engine overwrites that buffer.
            asm volatile("s_waitcnt lgkmcnt(0)" ::: "memory");
            const float* g = logits + (size_t)(t0 + i + 1) * TFLOATS;
            #pragma unroll
            for (int k = 0; k < 6; ++k)
                dma16(g + k * 256 + lane * 4, nxt + k * 256);
            dma4(g + 1536 + lane, nxt + 1536);
            // counted wait: 7 just-issued stay in flight; tile i's 7 landed.
            asm volatile("s_waitcnt vmcnt(7)" ::: "memory");
        } else {
            asm volatile("s_waitcnt vmcnt(0)" ::: "memory");
        }
        __builtin_amdgcn_sched_barrier(0);

        // ---- consume: 4 lanes per row, 25 cols each (wave-synchronous) ----
        const int lab = my_lab[i * TROWS + r];      // LDS read, no vmcnt
        const float* srow = cur + r * CCLS + q * 25;
        float m = -1e30f, e = 0.f;
        #pragma unroll
        for (int c = 0; c < 25; ++c) {
            const float x = srow[c];
            m = fmaxf(m, x);
            e += __expf(x);
        }
        float tp = 0.f;
        if (lab / 25 == q)                          // owning quarter
            tp = __expf(cur[r * CCLS + lab]);

        #pragma unroll
        for (int off = 16; off <= 32; off <<= 1) {
            m  = fmaxf(m, __shfl_xor(m, off));
            e  += __shfl_xor(e, off);
            tp += __shfl_xor(tp, off);
        }

        if (q == 0) {
            const float inv  = 1.0f / e;
            const float conf = __expf(m) * inv;
            const float diff = conf - tp * inv;
            int bin = (int)(conf * (float)NUM_BINS);
            bin = bin > NUM_BINS - 1 ? NUM_BINS - 1 : bin;
            atomicAdd(&s_bin[bin], diff);
        }

        float* tmp = cur; cur = nxt; nxt = tmp;
    }

    __syncthreads();
    if (tid < NUM_BINS) atomicAdd(&ws[tid], s_bin[tid]);
    __syncthreads();

    // ---- ticket: last block folds ECE = sum_b |ws[b]| / N ----
    if (tid == 0) {
        __threadfence();
        const int tkt = atomicAdd((int*)(ws + 48), 1);
        s_last = (tkt == GRID - 1) ? 1 : 0;
    }
    __syncthreads();
    if (s_last && tid < 64) {
        __threadfence();
        float contrib = 0.f;
        if (tid < NUM_BINS) {
            const float v = __hip_atomic_load(&ws[tid], __ATOMIC_RELAXED,
                                              __HIP_MEMORY_SCOPE_AGENT);
            contrib = fabsf(v);
        }
        #pragma unroll
        for (int off = 32; off >= 1; off >>= 1)
            contrib += __shfl_xor(contrib, off);
        if (tid == 0) out[0] = contrib / (float)n_rows;
    }
}

extern "C" void kernel_launch(void* const* d_in, const int* in_sizes, int n_in,
                              void* d_out, int out_size, void* d_ws, size_t ws_size,
                              hipStream_t stream)
{
    const float* logits = (const float*)d_in[0];
    const int*   labels = (const int*)d_in[1];
    float* out = (float*)d_out;
    float* ws  = (float*)d_ws;

    const int n_rows = in_sizes[1];   // 524288

    // ws re-poisoned to 0xAA before every timed launch — zero accumulators+ticket.
    hipMemsetAsync(ws, 0, 64 * sizeof(float), stream);

    ece_stream<<<dim3(GRID), dim3(BLOCK), 0, stream>>>(logits, labels, ws, out, n_rows);
}